// Round 1
// baseline (5123.441 us; speedup 1.0000x reference)
//
#include <hip/hip_runtime.h>
#include <cstdint>

#define NN 50000
#define DD 128
#define EE 600000

__device__ __forceinline__ float sigmoid_f(float x) {
    return 1.0f / (1.0f + __expf(-x));
}
__device__ __forceinline__ float tanh_f(float x) {
    float e = __expf(-2.0f * fabsf(x));
    float t = (1.0f - e) / (1.0f + e);
    return copysignf(t, x);
}

// w [384][128] -> wt [128][384] so K-chunks of weight are contiguous panels
__global__ __launch_bounds__(256) void transpose_w_kernel(const float* __restrict__ w,
                                                          float* __restrict__ wt) {
    int idx = blockIdx.x * 256 + threadIdx.x;
    if (idx >= 384 * DD) return;
    int c = idx >> 7;          // row in w (0..383)
    int k = idx & (DD - 1);    // col in w (0..127)
    wt[k * 384 + c] = w[idx];
}

// res[r] += v * x[c], 32 threads per edge (float4 per thread)
__global__ __launch_bounds__(256) void spmm_kernel(const float* __restrict__ x,
                                                   const int* __restrict__ rows,
                                                   const int* __restrict__ cols,
                                                   const float* __restrict__ vals,
                                                   float* __restrict__ res) {
    unsigned idx = blockIdx.x * 256u + threadIdx.x;
    unsigned e = idx >> 5;
    if (e >= EE) return;
    int d0 = (idx & 31) * 4;
    int r = rows[e];
    int c = cols[e];
    float v = vals[e];
    float4 xv = *reinterpret_cast<const float4*>(x + (size_t)c * DD + d0);
    float* dst = res + (size_t)r * DD + d0;
    unsafeAtomicAdd(dst + 0, v * xv.x);
    unsafeAtomicAdd(dst + 1, v * xv.y);
    unsafeAtomicAdd(dst + 2, v * xv.z);
    unsafeAtomicAdd(dst + 3, v * xv.w);
}

// Fused: gate_x = relu(res)@wx^T + bx ; gate_h = h@wh^T + bh ; GRU combine ; h <- hy
// Block: 32 rows x 128 cols, 256 threads, thread = 4 rows x 4 contiguous j.
__global__ __launch_bounds__(256, 2) void gru_step_kernel(const float* __restrict__ res,
                                                          float* __restrict__ h,
                                                          const float* __restrict__ wxT,
                                                          const float* __restrict__ bx,
                                                          const float* __restrict__ whT,
                                                          const float* __restrict__ bh) {
    __shared__ float s_res[32 * DD];   // 16 KB, relu applied
    __shared__ float s_h[32 * DD];     // 16 KB
    __shared__ float s_wx[4 * 384];    // 6 KB  (k-chunk of wxT)
    __shared__ float s_wh[4 * 384];    // 6 KB

    const int tid = threadIdx.x;
    const int row0 = blockIdx.x * 32;

    // stage 32 rows of relu(res) and h
    #pragma unroll
    for (int p = 0; p < 4; ++p) {
        int i = tid + p * 256;
        int rl = i >> 5;
        int f4 = (i & 31) * 4;
        int row = row0 + rl;
        float4 rv = make_float4(0.f, 0.f, 0.f, 0.f);
        float4 hv = make_float4(0.f, 0.f, 0.f, 0.f);
        if (row < NN) {
            rv = *reinterpret_cast<const float4*>(res + (size_t)row * DD + f4);
            hv = *reinterpret_cast<const float4*>(h + (size_t)row * DD + f4);
        }
        rv.x = fmaxf(rv.x, 0.f); rv.y = fmaxf(rv.y, 0.f);
        rv.z = fmaxf(rv.z, 0.f); rv.w = fmaxf(rv.w, 0.f);
        *reinterpret_cast<float4*>(&s_res[rl * DD + f4]) = rv;
        *reinterpret_cast<float4*>(&s_h[rl * DD + f4]) = hv;
    }

    const int tj = tid & 31;
    const int rt = tid >> 5;   // 0..7
    const int jb = tj * 4;     // j base (contiguous 4)

    // accumulators: Sr = i_r+h_r, Si = i_i+h_i, Sn = i_n, Hn = h_n
    float sr[4][4], si[4][4], sn[4][4], hn[4][4];
    {
        float4 bxr = *reinterpret_cast<const float4*>(bx + jb);
        float4 bxi = *reinterpret_cast<const float4*>(bx + DD + jb);
        float4 bxn = *reinterpret_cast<const float4*>(bx + 2 * DD + jb);
        float4 bhr = *reinterpret_cast<const float4*>(bh + jb);
        float4 bhi = *reinterpret_cast<const float4*>(bh + DD + jb);
        float4 bhn = *reinterpret_cast<const float4*>(bh + 2 * DD + jb);
        #pragma unroll
        for (int r = 0; r < 4; ++r) {
            sr[r][0] = bxr.x + bhr.x; sr[r][1] = bxr.y + bhr.y;
            sr[r][2] = bxr.z + bhr.z; sr[r][3] = bxr.w + bhr.w;
            si[r][0] = bxi.x + bhi.x; si[r][1] = bxi.y + bhi.y;
            si[r][2] = bxi.z + bhi.z; si[r][3] = bxi.w + bhi.w;
            sn[r][0] = bxn.x; sn[r][1] = bxn.y; sn[r][2] = bxn.z; sn[r][3] = bxn.w;
            hn[r][0] = bhn.x; hn[r][1] = bhn.y; hn[r][2] = bhn.z; hn[r][3] = bhn.w;
        }
    }

    for (int k0 = 0; k0 < DD; k0 += 4) {
        __syncthreads();  // protects s_w reuse; first iter also fences input staging
        // stage weight k-chunk: rows k0..k0+3 of wxT/whT = contiguous 6 KB each
        {
            *reinterpret_cast<float4*>(&s_wx[tid * 4]) =
                *reinterpret_cast<const float4*>(wxT + (size_t)k0 * 384 + tid * 4);
            *reinterpret_cast<float4*>(&s_wh[tid * 4]) =
                *reinterpret_cast<const float4*>(whT + (size_t)k0 * 384 + tid * 4);
            if (tid < 128) {
                int i = tid + 256;
                *reinterpret_cast<float4*>(&s_wx[i * 4]) =
                    *reinterpret_cast<const float4*>(wxT + (size_t)k0 * 384 + i * 4);
                *reinterpret_cast<float4*>(&s_wh[i * 4]) =
                    *reinterpret_cast<const float4*>(whT + (size_t)k0 * 384 + i * 4);
            }
        }
        __syncthreads();

        float av[4][4], bv[4][4];
        #pragma unroll
        for (int r = 0; r < 4; ++r) {
            float4 t = *reinterpret_cast<const float4*>(&s_res[(rt * 4 + r) * DD + k0]);
            av[r][0] = t.x; av[r][1] = t.y; av[r][2] = t.z; av[r][3] = t.w;
            float4 u = *reinterpret_cast<const float4*>(&s_h[(rt * 4 + r) * DD + k0]);
            bv[r][0] = u.x; bv[r][1] = u.y; bv[r][2] = u.z; bv[r][3] = u.w;
        }

        #pragma unroll
        for (int kk = 0; kk < 4; ++kk) {
            float4 wr = *reinterpret_cast<const float4*>(&s_wx[kk * 384 + jb]);
            float4 wi = *reinterpret_cast<const float4*>(&s_wx[kk * 384 + DD + jb]);
            float4 wn = *reinterpret_cast<const float4*>(&s_wx[kk * 384 + 2 * DD + jb]);
            float4 vr = *reinterpret_cast<const float4*>(&s_wh[kk * 384 + jb]);
            float4 vi = *reinterpret_cast<const float4*>(&s_wh[kk * 384 + DD + jb]);
            float4 vn = *reinterpret_cast<const float4*>(&s_wh[kk * 384 + 2 * DD + jb]);
            #pragma unroll
            for (int r = 0; r < 4; ++r) {
                float a = av[r][kk];
                float b = bv[r][kk];
                sr[r][0] += a * wr.x + b * vr.x;
                sr[r][1] += a * wr.y + b * vr.y;
                sr[r][2] += a * wr.z + b * vr.z;
                sr[r][3] += a * wr.w + b * vr.w;
                si[r][0] += a * wi.x + b * vi.x;
                si[r][1] += a * wi.y + b * vi.y;
                si[r][2] += a * wi.z + b * vi.z;
                si[r][3] += a * wi.w + b * vi.w;
                sn[r][0] += a * wn.x;
                sn[r][1] += a * wn.y;
                sn[r][2] += a * wn.z;
                sn[r][3] += a * wn.w;
                hn[r][0] += b * vn.x;
                hn[r][1] += b * vn.y;
                hn[r][2] += b * vn.z;
                hn[r][3] += b * vn.w;
            }
        }
    }

    // GRU epilogue, write hy in place (rows are block-private)
    #pragma unroll
    for (int r = 0; r < 4; ++r) {
        int row = row0 + rt * 4 + r;
        if (row >= NN) continue;
        float4 hold = *reinterpret_cast<const float4*>(&s_h[(rt * 4 + r) * DD + jb]);
        float ho[4] = {hold.x, hold.y, hold.z, hold.w};
        float o[4];
        #pragma unroll
        for (int jj = 0; jj < 4; ++jj) {
            float rg = sigmoid_f(sr[r][jj]);
            float ig = sigmoid_f(si[r][jj]);
            float ng = tanh_f(sn[r][jj] + rg * hn[r][jj]);
            o[jj] = ng + ig * (ho[jj] - ng);
        }
        *reinterpret_cast<float4*>(h + (size_t)row * DD + jb) =
            make_float4(o[0], o[1], o[2], o[3]);
    }
}

// LayerNorm over D=128, 32 lanes/row, two-pass variance (matches jnp.var)
__global__ __launch_bounds__(256) void ln_kernel(float* __restrict__ h,
                                                 const float* __restrict__ g,
                                                 const float* __restrict__ b) {
    int tid = threadIdx.x;
    int lane = tid & 31;
    int rl = tid >> 5;
    int row = blockIdx.x * 8 + rl;
    if (row >= NN) return;
    float4 v = *reinterpret_cast<const float4*>(h + (size_t)row * DD + lane * 4);
    float s = v.x + v.y + v.z + v.w;
    #pragma unroll
    for (int m = 16; m >= 1; m >>= 1) s += __shfl_xor(s, m, 64);
    float mean = s * (1.0f / DD);
    float dx = v.x - mean, dy = v.y - mean, dz = v.z - mean, dw = v.w - mean;
    float q = dx * dx + dy * dy + dz * dz + dw * dw;
    #pragma unroll
    for (int m = 16; m >= 1; m >>= 1) q += __shfl_xor(q, m, 64);
    float var = q * (1.0f / DD);
    float inv = 1.0f / sqrtf(var + 1e-5f);
    float4 gv = *reinterpret_cast<const float4*>(g + lane * 4);
    float4 bv = *reinterpret_cast<const float4*>(b + lane * 4);
    float4 o;
    o.x = dx * inv * gv.x + bv.x;
    o.y = dy * inv * gv.y + bv.y;
    o.z = dz * inv * gv.z + bv.z;
    o.w = dw * inv * gv.w + bv.w;
    *reinterpret_cast<float4*>(h + (size_t)row * DD + lane * 4) = o;
}

extern "C" void kernel_launch(void* const* d_in, const int* in_sizes, int n_in,
                              void* d_out, int out_size, void* d_ws, size_t ws_size,
                              hipStream_t stream) {
    const float* x    = (const float*)d_in[0];
    const float* vals = (const float*)d_in[1];
    const float* wx   = (const float*)d_in[2];
    const float* bx   = (const float*)d_in[3];
    const float* wh   = (const float*)d_in[4];
    const float* bh   = (const float*)d_in[5];
    const float* lng  = (const float*)d_in[6];
    const float* lnb  = (const float*)d_in[7];
    const int* rows   = (const int*)d_in[8];
    const int* cols   = (const int*)d_in[9];

    float* h = (float*)d_out;                                  // [N,128] hidden state
    float* res = (float*)d_ws;                                 // 25.6 MB
    float* wxT = (float*)((char*)d_ws + (size_t)NN * DD * 4);  // 384*128 f32
    float* whT = wxT + 384 * DD;

    (void)in_sizes; (void)n_in; (void)out_size; (void)ws_size;

    hipMemsetAsync(h, 0, (size_t)NN * DD * sizeof(float), stream);   // h0 = 0
    transpose_w_kernel<<<192, 256, 0, stream>>>(wx, wxT);
    transpose_w_kernel<<<192, 256, 0, stream>>>(wh, whT);

    const int spmm_grid = (EE * 32) / 256;        // 75000
    const int gru_grid = (NN + 31) / 32;          // 1563

    for (int s = 0; s < 4; ++s) {
        int k = 3 - s;  // adj_list reversed
        hipMemsetAsync(res, 0, (size_t)NN * DD * sizeof(float), stream);
        spmm_kernel<<<spmm_grid, 256, 0, stream>>>(
            x, rows + (size_t)k * EE, cols + (size_t)k * EE, vals + (size_t)k * EE, res);
        gru_step_kernel<<<gru_grid, 256, 0, stream>>>(res, h, wxT, bx, whT, bh);
    }

    ln_kernel<<<(NN + 7) / 8, 256, 0, stream>>>(h, lng, lnb);
}

// Round 2
// 1909.848 us; speedup vs baseline: 2.6826x; 2.6826x over previous
//
#include <hip/hip_runtime.h>
#include <cstdint>

#define NN 50000
#define DD 128
#define EE 600000

__device__ __forceinline__ float sigmoid_f(float x) {
    return 1.0f / (1.0f + __expf(-x));
}
__device__ __forceinline__ float tanh_f(float x) {
    float e = __expf(-2.0f * fabsf(x));
    float t = (1.0f - e) / (1.0f + e);
    return copysignf(t, x);
}

// w [384][128] -> wt [128][384] so K-chunks of weight are contiguous panels
__global__ __launch_bounds__(256) void transpose_w_kernel(const float* __restrict__ w,
                                                          float* __restrict__ wt) {
    int idx = blockIdx.x * 256 + threadIdx.x;
    if (idx >= 384 * DD) return;
    int c = idx >> 7;          // row in w (0..383)
    int k = idx & (DD - 1);    // col in w (0..127)
    wt[k * 384 + c] = w[idx];
}

// ---- CSR build ----------------------------------------------------------

__global__ __launch_bounds__(256) void hist_kernel(const int* __restrict__ rows,
                                                   int* __restrict__ cnt) {
    int e = blockIdx.x * 256 + threadIdx.x;
    if (e >= EE) return;
    atomicAdd(&cnt[rows[e]], 1);
}

// exclusive scan of cnt[0..NN) -> row_ptr[0..NN]; single block of 1024
__global__ __launch_bounds__(1024) void scan_kernel(const int* __restrict__ cnt,
                                                    int* __restrict__ row_ptr) {
    __shared__ int buf[1024];
    const int tid = threadIdx.x;
    const int CH = (NN + 1023) / 1024;  // 49
    const int base = tid * CH;
    int s = 0;
    #pragma unroll
    for (int i = 0; i < CH; ++i) {
        int idx = base + i;
        if (idx < NN) s += cnt[idx];
    }
    buf[tid] = s;
    __syncthreads();
    for (int d = 1; d < 1024; d <<= 1) {
        int t = (tid >= d) ? buf[tid - d] : 0;
        __syncthreads();
        buf[tid] += t;
        __syncthreads();
    }
    int run = buf[tid] - s;  // exclusive offset for this chunk
    #pragma unroll
    for (int i = 0; i < CH; ++i) {
        int idx = base + i;
        if (idx < NN) {
            row_ptr[idx] = run;
            run += cnt[idx];
        }
    }
    if (tid == 0) row_ptr[NN] = EE;
}

__global__ __launch_bounds__(256) void scatter_kernel(const int* __restrict__ rows,
                                                      const int* __restrict__ cols,
                                                      const float* __restrict__ vals,
                                                      int* __restrict__ cursor,
                                                      int* __restrict__ ecol,
                                                      float* __restrict__ eval) {
    int e = blockIdx.x * 256 + threadIdx.x;
    if (e >= EE) return;
    int r = rows[e];
    int pos = atomicAdd(&cursor[r], 1);
    ecol[pos] = cols[e];
    eval[pos] = vals[e];
}

// ---- SpMM as CSR gather: res[r] = relu(sum_e val*x[col]) ---------------
// one wave64 per row, float2 per lane
__global__ __launch_bounds__(256) void gather_kernel(const float* __restrict__ x,
                                                     const int* __restrict__ row_ptr,
                                                     const int* __restrict__ ecol,
                                                     const float* __restrict__ eval,
                                                     float* __restrict__ res) {
    const int tid = threadIdx.x;
    const int lane = tid & 63;
    const int row = blockIdx.x * 4 + (tid >> 6);
    if (row >= NN) return;
    const int start = row_ptr[row];
    const int end = row_ptr[row + 1];
    const int d0 = lane * 2;
    float ax = 0.f, ay = 0.f, bx2 = 0.f, by2 = 0.f;
    int e = start;
    for (; e + 1 < end; e += 2) {
        int c0 = ecol[e];
        int c1 = ecol[e + 1];
        float v0 = eval[e];
        float v1 = eval[e + 1];
        float2 a = *reinterpret_cast<const float2*>(x + (size_t)c0 * DD + d0);
        float2 b = *reinterpret_cast<const float2*>(x + (size_t)c1 * DD + d0);
        ax += v0 * a.x; ay += v0 * a.y;
        bx2 += v1 * b.x; by2 += v1 * b.y;
    }
    if (e < end) {
        int c0 = ecol[e];
        float v0 = eval[e];
        float2 a = *reinterpret_cast<const float2*>(x + (size_t)c0 * DD + d0);
        ax += v0 * a.x; ay += v0 * a.y;
    }
    float2 o;
    o.x = fmaxf(ax + bx2, 0.f);
    o.y = fmaxf(ay + by2, 0.f);
    *reinterpret_cast<float2*>(res + (size_t)row * DD + d0) = o;
}

// ---- Fused dual-GEMM + GRU ---------------------------------------------
// res already has relu applied. Block: 32 rows x 128 cols, 256 threads.
__global__ __launch_bounds__(256, 2) void gru_step_kernel(const float* __restrict__ res,
                                                          float* __restrict__ h,
                                                          const float* __restrict__ wxT,
                                                          const float* __restrict__ bx,
                                                          const float* __restrict__ whT,
                                                          const float* __restrict__ bh) {
    __shared__ float s_res[32 * DD];   // 16 KB
    __shared__ float s_h[32 * DD];     // 16 KB
    __shared__ float s_wx[4 * 384];    // 6 KB
    __shared__ float s_wh[4 * 384];    // 6 KB

    const int tid = threadIdx.x;
    const int row0 = blockIdx.x * 32;

    #pragma unroll
    for (int p = 0; p < 4; ++p) {
        int i = tid + p * 256;
        int rl = i >> 5;
        int f4 = (i & 31) * 4;
        int row = row0 + rl;
        float4 rv = make_float4(0.f, 0.f, 0.f, 0.f);
        float4 hv = make_float4(0.f, 0.f, 0.f, 0.f);
        if (row < NN) {
            rv = *reinterpret_cast<const float4*>(res + (size_t)row * DD + f4);
            hv = *reinterpret_cast<const float4*>(h + (size_t)row * DD + f4);
        }
        *reinterpret_cast<float4*>(&s_res[rl * DD + f4]) = rv;
        *reinterpret_cast<float4*>(&s_h[rl * DD + f4]) = hv;
    }

    const int tj = tid & 31;
    const int rt = tid >> 5;   // 0..7
    const int jb = tj * 4;

    float sr[4][4], si[4][4], sn[4][4], hn[4][4];
    {
        float4 bxr = *reinterpret_cast<const float4*>(bx + jb);
        float4 bxi = *reinterpret_cast<const float4*>(bx + DD + jb);
        float4 bxn = *reinterpret_cast<const float4*>(bx + 2 * DD + jb);
        float4 bhr = *reinterpret_cast<const float4*>(bh + jb);
        float4 bhi = *reinterpret_cast<const float4*>(bh + DD + jb);
        float4 bhn = *reinterpret_cast<const float4*>(bh + 2 * DD + jb);
        #pragma unroll
        for (int r = 0; r < 4; ++r) {
            sr[r][0] = bxr.x + bhr.x; sr[r][1] = bxr.y + bhr.y;
            sr[r][2] = bxr.z + bhr.z; sr[r][3] = bxr.w + bhr.w;
            si[r][0] = bxi.x + bhi.x; si[r][1] = bxi.y + bhi.y;
            si[r][2] = bxi.z + bhi.z; si[r][3] = bxi.w + bhi.w;
            sn[r][0] = bxn.x; sn[r][1] = bxn.y; sn[r][2] = bxn.z; sn[r][3] = bxn.w;
            hn[r][0] = bhn.x; hn[r][1] = bhn.y; hn[r][2] = bhn.z; hn[r][3] = bhn.w;
        }
    }

    for (int k0 = 0; k0 < DD; k0 += 4) {
        __syncthreads();
        {
            *reinterpret_cast<float4*>(&s_wx[tid * 4]) =
                *reinterpret_cast<const float4*>(wxT + (size_t)k0 * 384 + tid * 4);
            *reinterpret_cast<float4*>(&s_wh[tid * 4]) =
                *reinterpret_cast<const float4*>(whT + (size_t)k0 * 384 + tid * 4);
            if (tid < 128) {
                int i = tid + 256;
                *reinterpret_cast<float4*>(&s_wx[i * 4]) =
                    *reinterpret_cast<const float4*>(wxT + (size_t)k0 * 384 + i * 4);
                *reinterpret_cast<float4*>(&s_wh[i * 4]) =
                    *reinterpret_cast<const float4*>(whT + (size_t)k0 * 384 + i * 4);
            }
        }
        __syncthreads();

        float av[4][4], bv[4][4];
        #pragma unroll
        for (int r = 0; r < 4; ++r) {
            float4 t = *reinterpret_cast<const float4*>(&s_res[(rt * 4 + r) * DD + k0]);
            av[r][0] = t.x; av[r][1] = t.y; av[r][2] = t.z; av[r][3] = t.w;
            float4 u = *reinterpret_cast<const float4*>(&s_h[(rt * 4 + r) * DD + k0]);
            bv[r][0] = u.x; bv[r][1] = u.y; bv[r][2] = u.z; bv[r][3] = u.w;
        }

        #pragma unroll
        for (int kk = 0; kk < 4; ++kk) {
            float4 wr = *reinterpret_cast<const float4*>(&s_wx[kk * 384 + jb]);
            float4 wi = *reinterpret_cast<const float4*>(&s_wx[kk * 384 + DD + jb]);
            float4 wn = *reinterpret_cast<const float4*>(&s_wx[kk * 384 + 2 * DD + jb]);
            float4 vr = *reinterpret_cast<const float4*>(&s_wh[kk * 384 + jb]);
            float4 vi = *reinterpret_cast<const float4*>(&s_wh[kk * 384 + DD + jb]);
            float4 vn = *reinterpret_cast<const float4*>(&s_wh[kk * 384 + 2 * DD + jb]);
            #pragma unroll
            for (int r = 0; r < 4; ++r) {
                float a = av[r][kk];
                float b = bv[r][kk];
                sr[r][0] += a * wr.x + b * vr.x;
                sr[r][1] += a * wr.y + b * vr.y;
                sr[r][2] += a * wr.z + b * vr.z;
                sr[r][3] += a * wr.w + b * vr.w;
                si[r][0] += a * wi.x + b * vi.x;
                si[r][1] += a * wi.y + b * vi.y;
                si[r][2] += a * wi.z + b * vi.z;
                si[r][3] += a * wi.w + b * vi.w;
                sn[r][0] += a * wn.x;
                sn[r][1] += a * wn.y;
                sn[r][2] += a * wn.z;
                sn[r][3] += a * wn.w;
                hn[r][0] += b * vn.x;
                hn[r][1] += b * vn.y;
                hn[r][2] += b * vn.z;
                hn[r][3] += b * vn.w;
            }
        }
    }

    #pragma unroll
    for (int r = 0; r < 4; ++r) {
        int row = row0 + rt * 4 + r;
        if (row >= NN) continue;
        float4 hold = *reinterpret_cast<const float4*>(&s_h[(rt * 4 + r) * DD + jb]);
        float ho[4] = {hold.x, hold.y, hold.z, hold.w};
        float o[4];
        #pragma unroll
        for (int jj = 0; jj < 4; ++jj) {
            float rg = sigmoid_f(sr[r][jj]);
            float ig = sigmoid_f(si[r][jj]);
            float ng = tanh_f(sn[r][jj] + rg * hn[r][jj]);
            o[jj] = ng + ig * (ho[jj] - ng);
        }
        *reinterpret_cast<float4*>(h + (size_t)row * DD + jb) =
            make_float4(o[0], o[1], o[2], o[3]);
    }
}

// LayerNorm over D=128, 32 lanes/row, two-pass variance (matches jnp.var)
__global__ __launch_bounds__(256) void ln_kernel(float* __restrict__ h,
                                                 const float* __restrict__ g,
                                                 const float* __restrict__ b) {
    int tid = threadIdx.x;
    int lane = tid & 31;
    int rl = tid >> 5;
    int row = blockIdx.x * 8 + rl;
    if (row >= NN) return;
    float4 v = *reinterpret_cast<const float4*>(h + (size_t)row * DD + lane * 4);
    float s = v.x + v.y + v.z + v.w;
    #pragma unroll
    for (int m = 16; m >= 1; m >>= 1) s += __shfl_xor(s, m, 64);
    float mean = s * (1.0f / DD);
    float dx = v.x - mean, dy = v.y - mean, dz = v.z - mean, dw = v.w - mean;
    float q = dx * dx + dy * dy + dz * dz + dw * dw;
    #pragma unroll
    for (int m = 16; m >= 1; m >>= 1) q += __shfl_xor(q, m, 64);
    float var = q * (1.0f / DD);
    float inv = 1.0f / sqrtf(var + 1e-5f);
    float4 gv = *reinterpret_cast<const float4*>(g + lane * 4);
    float4 bv = *reinterpret_cast<const float4*>(b + lane * 4);
    float4 o;
    o.x = dx * inv * gv.x + bv.x;
    o.y = dy * inv * gv.y + bv.y;
    o.z = dz * inv * gv.z + bv.z;
    o.w = dw * inv * gv.w + bv.w;
    *reinterpret_cast<float4*>(h + (size_t)row * DD + lane * 4) = o;
}

extern "C" void kernel_launch(void* const* d_in, const int* in_sizes, int n_in,
                              void* d_out, int out_size, void* d_ws, size_t ws_size,
                              hipStream_t stream) {
    const float* x    = (const float*)d_in[0];
    const float* vals = (const float*)d_in[1];
    const float* wx   = (const float*)d_in[2];
    const float* bx   = (const float*)d_in[3];
    const float* wh   = (const float*)d_in[4];
    const float* bh   = (const float*)d_in[5];
    const float* lng  = (const float*)d_in[6];
    const float* lnb  = (const float*)d_in[7];
    const int* rows   = (const int*)d_in[8];
    const int* cols   = (const int*)d_in[9];

    char* ws = (char*)d_ws;
    float* h   = (float*)d_out;
    float* res = (float*)ws;                       ws += (size_t)NN * DD * 4;   // 25.6 MB
    float* wxT = (float*)ws;                       ws += 384 * DD * 4;
    float* whT = (float*)ws;                       ws += 384 * DD * 4;
    int* row_ptr = (int*)ws;                       ws += ((NN + 1 + 63) / 64) * 64 * 4;
    int* cnt     = (int*)ws;                       ws += ((NN + 63) / 64) * 64 * 4;
    int* cursor  = (int*)ws;                       ws += ((NN + 63) / 64) * 64 * 4;
    int* ecol    = (int*)ws;                       ws += (size_t)EE * 4;
    float* eval  = (float*)ws;                     ws += (size_t)EE * 4;

    (void)in_sizes; (void)n_in; (void)out_size; (void)ws_size;

    hipMemsetAsync(h, 0, (size_t)NN * DD * sizeof(float), stream);   // h0 = 0
    transpose_w_kernel<<<192, 256, 0, stream>>>(wx, wxT);
    transpose_w_kernel<<<192, 256, 0, stream>>>(wh, whT);

    const int egrid = (EE + 255) / 256;           // 2344
    const int ggrid = (NN + 3) / 4;               // 12500
    const int gru_grid = (NN + 31) / 32;          // 1563

    for (int s = 0; s < 4; ++s) {
        int k = 3 - s;  // adj_list reversed
        const int* kr = rows + (size_t)k * EE;
        const int* kc = cols + (size_t)k * EE;
        const float* kv = vals + (size_t)k * EE;

        hipMemsetAsync(cnt, 0, NN * sizeof(int), stream);
        hist_kernel<<<egrid, 256, 0, stream>>>(kr, cnt);
        scan_kernel<<<1, 1024, 0, stream>>>(cnt, row_ptr);
        hipMemcpyAsync(cursor, row_ptr, NN * sizeof(int), hipMemcpyDeviceToDevice, stream);
        scatter_kernel<<<egrid, 256, 0, stream>>>(kr, kc, kv, cursor, ecol, eval);
        gather_kernel<<<ggrid, 256, 0, stream>>>(x, row_ptr, ecol, eval, res);

        gru_step_kernel<<<gru_grid, 256, 0, stream>>>(res, h, wxT, bx, whT, bh);
    }

    ln_kernel<<<(NN + 7) / 8, 256, 0, stream>>>(h, lng, lnb);
}